// Round 4
// baseline (427.182 us; speedup 1.0000x reference)
//
#include <hip/hip_runtime.h>

typedef __bf16 bf16_t;
typedef __bf16 bf16x2 __attribute__((ext_vector_type(2)));
typedef __bf16 bf16x4 __attribute__((ext_vector_type(4)));
typedef __bf16 bf16x8 __attribute__((ext_vector_type(8)));
typedef float floatx4 __attribute__((ext_vector_type(4)));
typedef float floatx16 __attribute__((ext_vector_type(16)));

#define S_H   (8 * 2048 * 256)   // elements per H buffer (4,194,304)

__device__ inline void split_hl(float v, bf16_t& hi, bf16_t& lo) {
    hi = (bf16_t)v;
    lo = (bf16_t)(v - (float)hi);
}

// ---------------- kernel 0: adj int32 -> bitmask (2048 rows x 64 words) ----------------
__global__ void adjbits_kernel(const int* __restrict__ adj, unsigned* __restrict__ bits) {
    int id = blockIdx.x * 256 + threadIdx.x;   // 131072 words
    const int* p = adj + (size_t)id * 32;
    unsigned w = 0;
#pragma unroll
    for (int j = 0; j < 32; j += 4) {
        int4 v = *(const int4*)(p + j);
        w |= (v.x > 0 ? 1u : 0u) << j;
        w |= (v.y > 0 ? 1u : 0u) << (j + 1);
        w |= (v.z > 0 ? 1u : 0u) << (j + 2);
        w |= (v.w > 0 ? 1u : 0u) << (j + 3);
    }
    bits[id] = w;
}

// ---------------- kernel 1: transpose + hi/lo split W ----------------
__global__ void wtrans_kernel(const float* __restrict__ W1,
                              const float* __restrict__ W2,
                              const float* __restrict__ W3,
                              bf16_t* __restrict__ Wthi, bf16_t* __restrict__ Wtlo) {
    __shared__ float T[64 * 68];
    const int zi = blockIdx.z;
    const float* W = (zi == 0) ? W1 : ((zi == 1) ? W2 : W3);
    bf16_t* ohi = Wthi + zi * 256 * 256;
    bf16_t* olo = Wtlo + zi * 256 * 256;
    const int c0 = blockIdx.x * 64, d0 = blockIdx.y * 64;
    const int tid = threadIdx.x;
#pragma unroll
    for (int i = 0; i < 4; i++) {
        int idx = i * 256 + tid;
        int r = idx >> 4, c4 = (idx & 15) * 4;
        floatx4 v = *(const floatx4*)(W + (c0 + r) * 256 + d0 + c4);
        *(floatx4*)(&T[r * 68 + c4]) = v;
    }
    __syncthreads();
#pragma unroll
    for (int i = 0; i < 4; i++) {
        int idx = i * 256 + tid;
        int rd = idx & 63, cc4 = (idx >> 6) * 4;
        bf16x4 vh, vl;
#pragma unroll
        for (int ii = 0; ii < 4; ii++) {
            float v = T[(cc4 + ii) * 68 + rd];
            bf16_t h, l; split_hl(v, h, l);
            vh[ii] = h; vl[ii] = l;
        }
        *(bf16x4*)(ohi + (d0 + rd) * 256 + c0 + cc4) = vh;
        *(bf16x4*)(olo + (d0 + rd) * 256 + c0 + cc4) = vl;
    }
}

// ---------------- kernel 2: projections ----------------
__global__ __launch_bounds__(256) void proj_kernel(
    const float* __restrict__ X,
    const bf16_t* __restrict__ Wthi, const bf16_t* __restrict__ Wtlo,
    bf16_t* __restrict__ H1hi, bf16_t* __restrict__ H1lo,
    bf16_t* __restrict__ H2hi, bf16_t* __restrict__ H2lo,
    bf16_t* __restrict__ H3t) {
    __shared__ bf16_t Xh[64 * 40], Xl[64 * 40];
    __shared__ bf16_t Wh[256 * 40], Wl[256 * 40];
    const int z = blockIdx.y;
    const int row0 = blockIdx.x * 64;
    const int tid = threadIdx.x;
    const int w = tid >> 6, lane = tid & 63;
    const int m = lane & 15, q = lane >> 4;
    const bf16_t* Wzh = Wthi + z * 256 * 256;
    const bf16_t* Wzl = Wtlo + z * 256 * 256;

    floatx4 acc[16];
#pragma unroll
    for (int i = 0; i < 16; i++) acc[i] = (floatx4){0.f, 0.f, 0.f, 0.f};

    for (int c0 = 0; c0 < 256; c0 += 32) {
#pragma unroll
        for (int i = 0; i < 2; i++) {
            int idx = i * 256 + tid;
            int r = idx >> 3, c4 = (idx & 7) * 4;
            floatx4 v = *(const floatx4*)(X + (row0 + r) * 256 + c0 + c4);
            bf16x4 vh, vl;
#pragma unroll
            for (int ii = 0; ii < 4; ii++) {
                bf16_t h, l; split_hl(v[ii], h, l);
                vh[ii] = h; vl[ii] = l;
            }
            *(bf16x4*)(&Xh[r * 40 + c4]) = vh;
            *(bf16x4*)(&Xl[r * 40 + c4]) = vl;
        }
#pragma unroll
        for (int i = 0; i < 4; i++) {
            int idx = i * 256 + tid;
            int d = idx >> 2, c8 = (idx & 3) * 8;
            *(bf16x8*)(&Wh[d * 40 + c8]) = *(const bf16x8*)(Wzh + d * 256 + c0 + c8);
            *(bf16x8*)(&Wl[d * 40 + c8]) = *(const bf16x8*)(Wzl + d * 256 + c0 + c8);
        }
        __syncthreads();
        bf16x8 ah = *(const bf16x8*)(&Xh[(w * 16 + m) * 40 + q * 8]);
        bf16x8 al = *(const bf16x8*)(&Xl[(w * 16 + m) * 40 + q * 8]);
#pragma unroll
        for (int nt = 0; nt < 16; nt++) {
            bf16x8 bh = *(const bf16x8*)(&Wh[(nt * 16 + m) * 40 + q * 8]);
            bf16x8 bl = *(const bf16x8*)(&Wl[(nt * 16 + m) * 40 + q * 8]);
            acc[nt] = __builtin_amdgcn_mfma_f32_16x16x32_bf16(ah, bh, acc[nt], 0, 0, 0);
            acc[nt] = __builtin_amdgcn_mfma_f32_16x16x32_bf16(ah, bl, acc[nt], 0, 0, 0);
            acc[nt] = __builtin_amdgcn_mfma_f32_16x16x32_bf16(al, bh, acc[nt], 0, 0, 0);
        }
        __syncthreads();
    }
    const int rbase = row0 + w * 16 + q * 4;
    if (z < 2) {
        bf16_t* Hhi = (z == 0) ? H1hi : H2hi;
        bf16_t* Hlo = (z == 0) ? H1lo : H2lo;
#pragma unroll
        for (int nt = 0; nt < 16; nt++)
#pragma unroll
            for (int r = 0; r < 4; r++) {
                bf16_t h, l; split_hl(acc[nt][r], h, l);
                int off = (rbase + r) * 256 + nt * 16 + m;
                Hhi[off] = h;
                Hlo[off] = l;
            }
    } else {
#pragma unroll
        for (int nt = 0; nt < 16; nt++)
#pragma unroll
            for (int r = 0; r < 4; r++) {
                int token = rbase + r;
                int b = token >> 11, n = token & 2047;
                H3t[(b * 256 + nt * 16 + m) * 2048 + n] = (bf16_t)acc[nt][r];
            }
    }
}

// ---------------- kernel 3: flash attention, S^T = K·Q^T via 32x32x16 MFMA ----------------
// Wave owns 32 q-rows (Q in registers, hi+lo). Block = 4 waves = 128 q-rows.
// Per-lane softmax state: q = lane&31 (both lane-halves keep identical m/l).
__global__ __launch_bounds__(256, 1) void attn_kernel(
    const bf16_t* __restrict__ H1hi, const bf16_t* __restrict__ H1lo,
    const bf16_t* __restrict__ H2hi, const bf16_t* __restrict__ H2lo,
    const bf16_t* __restrict__ H3t, const unsigned* __restrict__ adjbits,
    float* __restrict__ Opart, float* __restrict__ mpart, float* __restrict__ lpart,
    int klen) {
    __shared__ bf16_t Kl[2][32 * 264];   // hi/lo K tile [32 keys][256 feat + pad]
    __shared__ bf16_t Vl[256 * 40];      // Vt tile [256 d][32 keys + pad]
    __shared__ bf16_t Pl[4][32 * 40];    // per-wave P buffer [32 q][32 keys + pad]

    const int b = blockIdx.y;
    const int q0b = blockIdx.x * 128;
    const int kz = blockIdx.z;
    const int tid = threadIdx.x;
    const int w = tid >> 6, lane = tid & 63;
    const int lq = lane & 31;            // q-column / key-row / d-row index
    const int h = lane >> 5;             // k-half selector

    const int qg = q0b + w * 32 + lq;    // this lane's global query row

    // ---- Q fragments in registers: B-layout B[k][n=q], hi+lo, 16 chunks of k=16 ----
    bf16x8 qhi[16], qlo[16];
    {
        const bf16_t* qrh = H1hi + (size_t)(b * 2048 + qg) * 256;
        const bf16_t* qrl = H1lo + (size_t)(b * 2048 + qg) * 256;
#pragma unroll
        for (int ck = 0; ck < 16; ck++) {
            qhi[ck] = *(const bf16x8*)(qrh + ck * 16 + h * 8);
            qlo[ck] = *(const bf16x8*)(qrl + ck * 16 + h * 8);
        }
    }

    float m_run = -3.0e38f, l_run = 0.f;
    floatx16 o[8];
#pragma unroll
    for (int t = 0; t < 8; t++) o[t] = (floatx16)(0.f);

    // staging assignments (constant per thread)
    const int kc8 = (tid & 31) * 8;      // K: feat offset, rows i*8 + (tid>>5)
    const int vk8 = (tid & 3) * 8;       // V: key offset, d = i*64 + (tid>>2)
    bf16x8 rkh[4], rkl[4], rvv[4];

    const int kbeg = kz * klen, kend = kbeg + klen;

    // prefetch first tile
#pragma unroll
    for (int i = 0; i < 4; i++) {
        int kr = i * 8 + (tid >> 5);
        rkh[i] = *(const bf16x8*)(H2hi + (size_t)(b * 2048 + kbeg + kr) * 256 + kc8);
        rkl[i] = *(const bf16x8*)(H2lo + (size_t)(b * 2048 + kbeg + kr) * 256 + kc8);
        int vd = i * 64 + (tid >> 2);
        rvv[i] = *(const bf16x8*)(H3t + (size_t)(b * 256 + vd) * 2048 + kbeg + vk8);
    }

    for (int k0 = kbeg; k0 < kend; k0 += 32) {
        __syncthreads();   // prior iter's LDS readers done
#pragma unroll
        for (int i = 0; i < 4; i++) {
            int kr = i * 8 + (tid >> 5);
            *(bf16x8*)(&Kl[0][kr * 264 + kc8]) = rkh[i];
            *(bf16x8*)(&Kl[1][kr * 264 + kc8]) = rkl[i];
            int vd = i * 64 + (tid >> 2);
            *(bf16x8*)(&Vl[vd * 40 + vk8]) = rvv[i];
        }
        __syncthreads();
        // prefetch next tile while computing this one
        if (k0 + 32 < kend) {
            int kn = k0 + 32;
#pragma unroll
            for (int i = 0; i < 4; i++) {
                int kr = i * 8 + (tid >> 5);
                rkh[i] = *(const bf16x8*)(H2hi + (size_t)(b * 2048 + kn + kr) * 256 + kc8);
                rkl[i] = *(const bf16x8*)(H2lo + (size_t)(b * 2048 + kn + kr) * 256 + kc8);
                int vd = i * 64 + (tid >> 2);
                rvv[i] = *(const bf16x8*)(H3t + (size_t)(b * 256 + vd) * 2048 + kn + vk8);
            }
        }

        // ---- S^T = K·Q^T : A = K-frag (m=key), B = Q-frag (n=q); 3 indep chains ----
        floatx16 sa = (floatx16)(0.f), sb = (floatx16)(0.f), sc = (floatx16)(0.f);
#pragma unroll
        for (int ck = 0; ck < 16; ck++) {
            bf16x8 kh = *(const bf16x8*)(&Kl[0][lq * 264 + ck * 16 + h * 8]);
            bf16x8 klo = *(const bf16x8*)(&Kl[1][lq * 264 + ck * 16 + h * 8]);
            sa = __builtin_amdgcn_mfma_f32_32x32x16_bf16(kh, qhi[ck], sa, 0, 0, 0);
            sb = __builtin_amdgcn_mfma_f32_32x32x16_bf16(kh, qlo[ck], sb, 0, 0, 0);
            sc = __builtin_amdgcn_mfma_f32_32x32x16_bf16(klo, qhi[ck], sc, 0, 0, 0);
        }

        // ---- leaky-relu + mask + per-q (per-lane) tile max ----
        unsigned aw = adjbits[(size_t)qg * 64 + (k0 >> 5)];
        unsigned awh = h ? (aw >> 4) : aw;     // fold key's +4h bit into the shift
        float p[16];
        float tmax = -3.0e38f;
#pragma unroll
        for (int r = 0; r < 16; r++) {
            float v = sa[r] + sb[r] + sc[r];
            v = (v > 0.f) ? v : 0.2f * v;
            int keyl = (r & 3) + 8 * (r >> 2);       // + 4h via awh
            v = ((awh >> keyl) & 1u) ? v : -1.0e12f;
            p[r] = v;
            tmax = fmaxf(tmax, v);
        }
        tmax = fmaxf(tmax, __shfl_xor(tmax, 32, 64));

        // ---- online softmax update (skip rescale when max didn't rise) ----
        float mnew = fmaxf(m_run, tmax);
        if (__any(mnew > m_run)) {
            float alpha = __expf(m_run - mnew);
            m_run = mnew;
            l_run *= alpha;
#pragma unroll
            for (int t = 0; t < 8; t++)
#pragma unroll
                for (int r = 0; r < 16; r++) o[t][r] *= alpha;
        }
        float rs = 0.f;
#pragma unroll
        for (int r = 0; r < 16; r++) {
            float e = __expf(p[r] - m_run);
            p[r] = e;
            rs += e;
        }
        rs += __shfl_xor(rs, 32, 64);
        l_run += rs;

        // ---- P -> per-wave LDS [q][key], then read B-layout frags ----
#pragma unroll
        for (int mreg = 0; mreg < 8; mreg++) {
            int keyl = 2 * (mreg & 1) + 8 * (mreg >> 1) + 4 * h;
            bf16x2 pk;
            pk[0] = (bf16_t)p[2 * mreg];
            pk[1] = (bf16_t)p[2 * mreg + 1];
            *(bf16x2*)(&Pl[w][lq * 40 + keyl]) = pk;
        }
        bf16x8 pf0 = *(const bf16x8*)(&Pl[w][lq * 40 + h * 8]);
        bf16x8 pf1 = *(const bf16x8*)(&Pl[w][lq * 40 + 16 + h * 8]);

        // ---- O^T += V^T·P : A = V-frag (m=d), B = P-frag (n=q) ----
#pragma unroll
        for (int t = 0; t < 8; t++) {
            bf16x8 v0 = *(const bf16x8*)(&Vl[(t * 32 + lq) * 40 + h * 8]);
            bf16x8 v1 = *(const bf16x8*)(&Vl[(t * 32 + lq) * 40 + 16 + h * 8]);
            o[t] = __builtin_amdgcn_mfma_f32_32x32x16_bf16(v0, pf0, o[t], 0, 0, 0);
            o[t] = __builtin_amdgcn_mfma_f32_32x32x16_bf16(v1, pf1, o[t], 0, 0, 0);
        }
    }

    // ---- epilogue: per-wave LDS transpose O^T -> row-major partials ----
    const int rowg = kz * 16384 + b * 2048 + q0b + w * 32;
    float* LT = ((float*)&Kl[0][0]) + w * 1152;   // 32 q x 36 d floats per wave
#pragma unroll 1
    for (int t = 0; t < 8; t++) {
        __syncthreads();
#pragma unroll
        for (int r = 0; r < 16; r++) {
            int dsub = (r & 3) + 8 * (r >> 2) + 4 * h;
            LT[lq * 36 + dsub] = o[t][r];
        }
        __syncthreads();
#pragma unroll
        for (int pp = 0; pp < 4; pp++) {
            int qq = pp * 8 + (lane >> 3), dc = (lane & 7) * 4;
            floatx4 v = *(const floatx4*)(&LT[qq * 36 + dc]);
            *(floatx4*)(&Opart[(size_t)(rowg + qq) * 256 + t * 32 + dc]) = v;
        }
    }
    if (h == 0) {
        mpart[rowg + lq] = m_run;
        lpart[rowg + lq] = l_run;
    }
}

// ---------------- kernel 4: merge splits + normalize + relu ----------------
__global__ __launch_bounds__(256) void merge_kernel(
    const float* __restrict__ Opart, const float* __restrict__ mpart,
    const float* __restrict__ lpart, float* __restrict__ out, int S) {
    int gid = blockIdx.x * 256 + threadIdx.x;     // 8*2048*64 float4 cols
    int row = gid >> 6, c4 = (gid & 63) * 4;
    float M = -3.0e38f;
    for (int s = 0; s < S; s++) M = fmaxf(M, mpart[s * 16384 + row]);
    float denom = 0.f;
    float4 acc = make_float4(0.f, 0.f, 0.f, 0.f);
    for (int s = 0; s < S; s++) {
        float sc = __expf(mpart[s * 16384 + row] - M);
        denom += lpart[s * 16384 + row] * sc;
        float4 v = *(const float4*)(Opart + ((size_t)(s * 16384 + row)) * 256 + c4);
        acc.x += v.x * sc; acc.y += v.y * sc; acc.z += v.z * sc; acc.w += v.w * sc;
    }
    float inv = 1.f / denom;
    float4 r;
    r.x = fmaxf(acc.x * inv, 0.f);
    r.y = fmaxf(acc.y * inv, 0.f);
    r.z = fmaxf(acc.z * inv, 0.f);
    r.w = fmaxf(acc.w * inv, 0.f);
    *(float4*)(out + (size_t)row * 256 + c4) = r;
}

extern "C" void kernel_launch(void* const* d_in, const int* in_sizes, int n_in,
                              void* d_out, int out_size, void* d_ws, size_t ws_size,
                              hipStream_t stream) {
    const float* X   = (const float*)d_in[0];
    const int*   adj = (const int*)d_in[1];
    const float* W1  = (const float*)d_in[2];
    const float* W2  = (const float*)d_in[3];
    const float* W3  = (const float*)d_in[4];
    float* out = (float*)d_out;

    char* ws = (char*)d_ws;
    bf16_t* H1hi = (bf16_t*)(ws + (size_t)0 * S_H * 2);
    bf16_t* H1lo = (bf16_t*)(ws + (size_t)1 * S_H * 2);
    bf16_t* H2hi = (bf16_t*)(ws + (size_t)2 * S_H * 2);
    bf16_t* H2lo = (bf16_t*)(ws + (size_t)3 * S_H * 2);
    bf16_t* H3t  = (bf16_t*)(ws + (size_t)4 * S_H * 2);
    size_t off = (size_t)5 * S_H * 2;                    // 41,943,040
    bf16_t* Wthi = (bf16_t*)(ws + off);                  // 393,216 B
    bf16_t* Wtlo = (bf16_t*)(ws + off + 393216);         // 393,216 B
    float* mpart = (float*)(ws + off);                   // overlays Wt (dead after proj)
    float* lpart = (float*)(ws + off + 131072);
    unsigned* adjb = (unsigned*)(ws + off + 786432);     // 524,288 B
    size_t opart_off = off + 786432 + 524288;
    const size_t need2 = opart_off + (size_t)2 * 16384 * 256 * 4;  // ~76.8 MB

    int S = (ws_size >= need2) ? 2 : 1;
    float* Opart = (S == 2) ? (float*)(ws + opart_off) : out;

    adjbits_kernel<<<512, 256, 0, stream>>>(adj, adjb);
    wtrans_kernel<<<dim3(4, 4, 3), 256, 0, stream>>>(W1, W2, W3, Wthi, Wtlo);
    proj_kernel<<<dim3(256, 3), 256, 0, stream>>>(X, Wthi, Wtlo,
                                                  H1hi, H1lo, H2hi, H2lo, H3t);
    attn_kernel<<<dim3(16, 8, S), 256, 0, stream>>>(H1hi, H1lo, H2hi, H2lo, H3t,
                                                    adjb, Opart, mpart, lpart, 2048 / S);
    merge_kernel<<<4096, 256, 0, stream>>>(Opart, mpart, lpart, out, S);
}

// Round 6
// 243.382 us; speedup vs baseline: 1.7552x; 1.7552x over previous
//
#include <hip/hip_runtime.h>

typedef __bf16 bf16_t;
typedef __bf16 bf16x4 __attribute__((ext_vector_type(4)));
typedef __bf16 bf16x8 __attribute__((ext_vector_type(8)));
typedef float floatx4 __attribute__((ext_vector_type(4)));

#define S_H   (8 * 2048 * 256)   // elements per H buffer (4,194,304)

__device__ inline void split_hl(float v, bf16_t& hi, bf16_t& lo) {
    hi = (bf16_t)v;
    lo = (bf16_t)(v - (float)hi);
}

// ---------------- kernel 0: adj int32 -> bitmask (2048 rows x 64 words) ----------------
__global__ void adjbits_kernel(const int* __restrict__ adj, unsigned* __restrict__ bits) {
    int id = blockIdx.x * 256 + threadIdx.x;   // 131072 words
    const int* p = adj + (size_t)id * 32;
    unsigned w = 0;
#pragma unroll
    for (int j = 0; j < 32; j += 4) {
        int4 v = *(const int4*)(p + j);
        w |= (v.x > 0 ? 1u : 0u) << j;
        w |= (v.y > 0 ? 1u : 0u) << (j + 1);
        w |= (v.z > 0 ? 1u : 0u) << (j + 2);
        w |= (v.w > 0 ? 1u : 0u) << (j + 3);
    }
    bits[id] = w;
}

// ---------------- kernel 1: transpose + hi/lo split W ----------------
__global__ void wtrans_kernel(const float* __restrict__ W1,
                              const float* __restrict__ W2,
                              const float* __restrict__ W3,
                              bf16_t* __restrict__ Wthi, bf16_t* __restrict__ Wtlo) {
    __shared__ float T[64 * 68];
    const int zi = blockIdx.z;
    const float* W = (zi == 0) ? W1 : ((zi == 1) ? W2 : W3);
    bf16_t* ohi = Wthi + zi * 256 * 256;
    bf16_t* olo = Wtlo + zi * 256 * 256;
    const int c0 = blockIdx.x * 64, d0 = blockIdx.y * 64;
    const int tid = threadIdx.x;
#pragma unroll
    for (int i = 0; i < 4; i++) {
        int idx = i * 256 + tid;
        int r = idx >> 4, c4 = (idx & 15) * 4;
        floatx4 v = *(const floatx4*)(W + (c0 + r) * 256 + d0 + c4);
        *(floatx4*)(&T[r * 68 + c4]) = v;
    }
    __syncthreads();
#pragma unroll
    for (int i = 0; i < 4; i++) {
        int idx = i * 256 + tid;
        int rd = idx & 63, cc4 = (idx >> 6) * 4;
        bf16x4 vh, vl;
#pragma unroll
        for (int ii = 0; ii < 4; ii++) {
            float v = T[(cc4 + ii) * 68 + rd];
            bf16_t h, l; split_hl(v, h, l);
            vh[ii] = h; vl[ii] = l;
        }
        *(bf16x4*)(ohi + (d0 + rd) * 256 + c0 + cc4) = vh;
        *(bf16x4*)(olo + (d0 + rd) * 256 + c0 + cc4) = vl;
    }
}

// ---------------- kernel 2: projections (X fp32, W hi/lo bf16) ----------------
__global__ __launch_bounds__(256) void proj_kernel(
    const float* __restrict__ X,
    const bf16_t* __restrict__ Wthi, const bf16_t* __restrict__ Wtlo,
    bf16_t* __restrict__ H1hi, bf16_t* __restrict__ H1lo,
    bf16_t* __restrict__ H2hi, bf16_t* __restrict__ H2lo,
    bf16_t* __restrict__ H3t) {
    __shared__ bf16_t Xh[64 * 40], Xl[64 * 40];
    __shared__ bf16_t Wh[256 * 40], Wl[256 * 40];
    const int z = blockIdx.y;
    const int row0 = blockIdx.x * 64;
    const int tid = threadIdx.x;
    const int w = tid >> 6, lane = tid & 63;
    const int m = lane & 15, q = lane >> 4;
    const bf16_t* Wzh = Wthi + z * 256 * 256;
    const bf16_t* Wzl = Wtlo + z * 256 * 256;

    floatx4 acc[16];
#pragma unroll
    for (int i = 0; i < 16; i++) acc[i] = (floatx4){0.f, 0.f, 0.f, 0.f};

    for (int c0 = 0; c0 < 256; c0 += 32) {
#pragma unroll
        for (int i = 0; i < 2; i++) {
            int idx = i * 256 + tid;
            int r = idx >> 3, c4 = (idx & 7) * 4;
            floatx4 v = *(const floatx4*)(X + (size_t)(row0 + r) * 256 + c0 + c4);
            bf16x4 vh, vl;
#pragma unroll
            for (int ii = 0; ii < 4; ii++) {
                bf16_t h, l; split_hl(v[ii], h, l);
                vh[ii] = h; vl[ii] = l;
            }
            *(bf16x4*)(&Xh[r * 40 + c4]) = vh;
            *(bf16x4*)(&Xl[r * 40 + c4]) = vl;
        }
#pragma unroll
        for (int i = 0; i < 4; i++) {
            int idx = i * 256 + tid;
            int d = idx >> 2, c8 = (idx & 3) * 8;
            *(bf16x8*)(&Wh[d * 40 + c8]) = *(const bf16x8*)(Wzh + d * 256 + c0 + c8);
            *(bf16x8*)(&Wl[d * 40 + c8]) = *(const bf16x8*)(Wzl + d * 256 + c0 + c8);
        }
        __syncthreads();
        bf16x8 ah = *(const bf16x8*)(&Xh[(w * 16 + m) * 40 + q * 8]);
        bf16x8 al = *(const bf16x8*)(&Xl[(w * 16 + m) * 40 + q * 8]);
#pragma unroll
        for (int nt = 0; nt < 16; nt++) {
            bf16x8 bh = *(const bf16x8*)(&Wh[(nt * 16 + m) * 40 + q * 8]);
            bf16x8 bl = *(const bf16x8*)(&Wl[(nt * 16 + m) * 40 + q * 8]);
            acc[nt] = __builtin_amdgcn_mfma_f32_16x16x32_bf16(ah, bh, acc[nt], 0, 0, 0);
            acc[nt] = __builtin_amdgcn_mfma_f32_16x16x32_bf16(ah, bl, acc[nt], 0, 0, 0);
            acc[nt] = __builtin_amdgcn_mfma_f32_16x16x32_bf16(al, bh, acc[nt], 0, 0, 0);
        }
        __syncthreads();
    }
    const int rbase = row0 + w * 16 + q * 4;
    if (z < 2) {
        bf16_t* Hhi = (z == 0) ? H1hi : H2hi;
        bf16_t* Hlo = (z == 0) ? H1lo : H2lo;
#pragma unroll
        for (int nt = 0; nt < 16; nt++)
#pragma unroll
            for (int r = 0; r < 4; r++) {
                bf16_t h, l; split_hl(acc[nt][r], h, l);
                int off = (rbase + r) * 256 + nt * 16 + m;
                Hhi[off] = h;
                Hlo[off] = l;
            }
    } else {
#pragma unroll
        for (int nt = 0; nt < 16; nt++)
#pragma unroll
            for (int r = 0; r < 4; r++) {
                int token = rbase + r;
                int b = token >> 11, n = token & 2047;
                H3t[(size_t)(b * 256 + nt * 16 + m) * 2048 + n] = (bf16_t)acc[nt][r];
            }
    }
}

// ---------------- kernel 3: flash attention, 512 threads = 8 waves = 128 queries ----------------
// Round-3 math verbatim (bf16 hi/lo, per-row m/l). One K/V tile feeds 128 queries.
// LDS 64.0 KB: Kl 2x32x260, Vl 256x40, Pl 8x16x40.
__global__ __launch_bounds__(512, 2) void attn_kernel(
    const bf16_t* __restrict__ H1hi, const bf16_t* __restrict__ H1lo,
    const bf16_t* __restrict__ H2hi, const bf16_t* __restrict__ H2lo,
    const bf16_t* __restrict__ H3t, const unsigned* __restrict__ adjbits,
    float* __restrict__ Opart, float* __restrict__ mpart, float* __restrict__ lpart,
    int klen) {
    __shared__ bf16_t Kl[2][32 * 260];   // hi/lo K tile [32 keys][256 feat + pad]
    __shared__ bf16_t Vl[256 * 40];      // Vt tile [256 d][32 k + pad]
    __shared__ bf16_t Pl[8][16 * 40];    // per-wave P round-trip

    const int b = blockIdx.y;
    const int q0 = blockIdx.x * 128;
    const int kz = blockIdx.z;
    const int tid = threadIdx.x;
    const int w = tid >> 6, lane = tid & 63;
    const int m = lane & 15, q = lane >> 4;

    // Q fragments (A-layout: row = lane&15), hi+lo split, K=256 -> 8 chunks
    const bf16_t* qrh = H1hi + (size_t)(b * 2048 + q0 + w * 16 + m) * 256;
    const bf16_t* qrl = H1lo + (size_t)(b * 2048 + q0 + w * 16 + m) * 256;
    bf16x8 qhi[8], qlo[8];
#pragma unroll
    for (int ck = 0; ck < 8; ck++) {
        qhi[ck] = *(const bf16x8*)(qrh + ck * 32 + q * 8);
        qlo[ck] = *(const bf16x8*)(qrl + ck * 32 + q * 8);
    }

    float m_run[4], l_run[4];
#pragma unroll
    for (int r = 0; r < 4; r++) { m_run[r] = -3.0e38f; l_run[r] = 0.f; }
    floatx4 o[16];
#pragma unroll
    for (int i = 0; i < 16; i++) o[i] = (floatx4){0.f, 0.f, 0.f, 0.f};

    const unsigned* bitrow[4];
#pragma unroll
    for (int r = 0; r < 4; r++)
        bitrow[r] = adjbits + (size_t)(q0 + w * 16 + q * 4 + r) * 64;

    // staging: 1024 chunks of K (hi+lo) and 1024 of V across 512 threads -> 2 each
    bf16x8 rkh[2], rkl[2], rvv[2];
    const int kbeg = kz * klen, kend = kbeg + klen;

#pragma unroll
    for (int i = 0; i < 2; i++) {   // prefetch first tile
        int ci = i * 512 + tid;
        int kr = ci >> 5, c8 = (ci & 31) * 8;
        rkh[i] = *(const bf16x8*)(H2hi + (size_t)(b * 2048 + kbeg + kr) * 256 + c8);
        rkl[i] = *(const bf16x8*)(H2lo + (size_t)(b * 2048 + kbeg + kr) * 256 + c8);
        int d = ci >> 2, k8 = (ci & 3) * 8;
        rvv[i] = *(const bf16x8*)(H3t + (size_t)(b * 256 + d) * 2048 + kbeg + k8);
    }

    for (int k0 = kbeg; k0 < kend; k0 += 32) {
        __syncthreads();   // prior iter's LDS readers done
#pragma unroll
        for (int i = 0; i < 2; i++) {
            int ci = i * 512 + tid;
            int kr = ci >> 5, c8 = (ci & 31) * 8;
            *(bf16x8*)(&Kl[0][kr * 260 + c8]) = rkh[i];
            *(bf16x8*)(&Kl[1][kr * 260 + c8]) = rkl[i];
            int d = ci >> 2, k8 = (ci & 3) * 8;
            *(bf16x8*)(&Vl[d * 40 + k8]) = rvv[i];
        }
        __syncthreads();
        if (k0 + 32 < kend) {   // prefetch next tile while computing
            int kn = k0 + 32;
#pragma unroll
            for (int i = 0; i < 2; i++) {
                int ci = i * 512 + tid;
                int kr = ci >> 5, c8 = (ci & 31) * 8;
                rkh[i] = *(const bf16x8*)(H2hi + (size_t)(b * 2048 + kn + kr) * 256 + c8);
                rkl[i] = *(const bf16x8*)(H2lo + (size_t)(b * 2048 + kn + kr) * 256 + c8);
                int d = ci >> 2, k8 = (ci & 3) * 8;
                rvv[i] = *(const bf16x8*)(H3t + (size_t)(b * 256 + d) * 2048 + kn + k8);
            }
        }

        // ---- S = Q K^T (hi*hi + hi*lo + lo*hi), 16 rows x 32 keys per wave ----
        floatx4 s[2];
#pragma unroll
        for (int t = 0; t < 2; t++) {
            floatx4 accs = (floatx4){0.f, 0.f, 0.f, 0.f};
#pragma unroll
            for (int ck = 0; ck < 8; ck++) {
                bf16x8 khi = *(const bf16x8*)(&Kl[0][(t * 16 + m) * 260 + ck * 32 + q * 8]);
                bf16x8 klo = *(const bf16x8*)(&Kl[1][(t * 16 + m) * 260 + ck * 32 + q * 8]);
                accs = __builtin_amdgcn_mfma_f32_16x16x32_bf16(qhi[ck], khi, accs, 0, 0, 0);
                accs = __builtin_amdgcn_mfma_f32_16x16x32_bf16(qhi[ck], klo, accs, 0, 0, 0);
                accs = __builtin_amdgcn_mfma_f32_16x16x32_bf16(qlo[ck], khi, accs, 0, 0, 0);
            }
            s[t] = accs;
        }

        // ---- leaky-relu + mask + tile row max ----
        unsigned aw[4];
#pragma unroll
        for (int r = 0; r < 4; r++) aw[r] = bitrow[r][k0 >> 5];
        float p[2][4], tmax[4];
#pragma unroll
        for (int r = 0; r < 4; r++) tmax[r] = -3.0e38f;
#pragma unroll
        for (int t = 0; t < 2; t++)
#pragma unroll
            for (int r = 0; r < 4; r++) {
                float v = s[t][r];
                v = (v > 0.f) ? v : 0.2f * v;
                v = ((aw[r] >> (t * 16 + m)) & 1u) ? v : -1.0e12f;
                p[t][r] = v;
                tmax[r] = fmaxf(tmax[r], v);
            }
#pragma unroll
        for (int off = 1; off < 16; off <<= 1)
#pragma unroll
            for (int r = 0; r < 4; r++)
                tmax[r] = fmaxf(tmax[r], __shfl_xor(tmax[r], off, 64));

        // ---- online softmax update (skip rescale when max didn't rise) ----
        int rise = 0;
        float mnew[4];
#pragma unroll
        for (int r = 0; r < 4; r++) {
            mnew[r] = fmaxf(m_run[r], tmax[r]);
            rise |= (mnew[r] > m_run[r]);
        }
        if (__any(rise)) {
#pragma unroll
            for (int r = 0; r < 4; r++) {
                float alpha = __expf(m_run[r] - mnew[r]);
                m_run[r] = mnew[r];
                l_run[r] *= alpha;
#pragma unroll
                for (int nt = 0; nt < 16; nt++) o[nt][r] *= alpha;
            }
        }
        float rsum[4];
#pragma unroll
        for (int r = 0; r < 4; r++) {
            float e0 = __expf(p[0][r] - m_run[r]);
            float e1 = __expf(p[1][r] - m_run[r]);
            p[0][r] = e0; p[1][r] = e1;
            rsum[r] = e0 + e1;
        }
#pragma unroll
        for (int off = 1; off < 16; off <<= 1)
#pragma unroll
            for (int r = 0; r < 4; r++)
                rsum[r] += __shfl_xor(rsum[r], off, 64);
#pragma unroll
        for (int r = 0; r < 4; r++) l_run[r] += rsum[r];

        // ---- P: C-layout -> per-wave LDS -> A-layout (no barrier) ----
#pragma unroll
        for (int t = 0; t < 2; t++)
#pragma unroll
            for (int r = 0; r < 4; r++)
                Pl[w][(q * 4 + r) * 40 + t * 16 + m] = (bf16_t)p[t][r];
        bf16x8 pf = *(const bf16x8*)(&Pl[w][m * 40 + q * 8]);

        // ---- O += P @ V ----
#pragma unroll
        for (int nt = 0; nt < 16; nt++) {
            bf16x8 vf = *(const bf16x8*)(&Vl[(nt * 16 + m) * 40 + q * 8]);
            o[nt] = __builtin_amdgcn_mfma_f32_16x16x32_bf16(pf, vf, o[nt], 0, 0, 0);
        }
    }

    // ---- epilogue: write unnormalized partials + per-row (m,l) ----
    const int rowg = kz * 16384 + b * 2048 + q0 + w * 16 + q * 4;
#pragma unroll
    for (int nt = 0; nt < 16; nt++)
#pragma unroll
        for (int r = 0; r < 4; r++)
            Opart[(size_t)(rowg + r) * 256 + nt * 16 + m] = o[nt][r];
    if (m == 0) {
#pragma unroll
        for (int r = 0; r < 4; r++) {
            mpart[rowg + r] = m_run[r];
            lpart[rowg + r] = l_run[r];
        }
    }
}

// ---------------- kernel 4: merge splits + normalize + relu ----------------
__global__ __launch_bounds__(256) void merge_kernel(
    const float* __restrict__ Opart, const float* __restrict__ mpart,
    const float* __restrict__ lpart, float* __restrict__ out, int S) {
    int gid = blockIdx.x * 256 + threadIdx.x;
    int row = gid >> 6, c4 = (gid & 63) * 4;
    float M = -3.0e38f;
    for (int s = 0; s < S; s++) M = fmaxf(M, mpart[s * 16384 + row]);
    float denom = 0.f;
    float4 acc = make_float4(0.f, 0.f, 0.f, 0.f);
    for (int s = 0; s < S; s++) {
        float sc = __expf(mpart[s * 16384 + row] - M);
        denom += lpart[s * 16384 + row] * sc;
        float4 v = *(const float4*)(Opart + ((size_t)(s * 16384 + row)) * 256 + c4);
        acc.x += v.x * sc; acc.y += v.y * sc; acc.z += v.z * sc; acc.w += v.w * sc;
    }
    float inv = 1.f / denom;
    float4 r;
    r.x = fmaxf(acc.x * inv, 0.f);
    r.y = fmaxf(acc.y * inv, 0.f);
    r.z = fmaxf(acc.z * inv, 0.f);
    r.w = fmaxf(acc.w * inv, 0.f);
    *(float4*)(out + (size_t)row * 256 + c4) = r;
}

extern "C" void kernel_launch(void* const* d_in, const int* in_sizes, int n_in,
                              void* d_out, int out_size, void* d_ws, size_t ws_size,
                              hipStream_t stream) {
    const float* X   = (const float*)d_in[0];
    const int*   adj = (const int*)d_in[1];
    const float* W1  = (const float*)d_in[2];
    const float* W2  = (const float*)d_in[3];
    const float* W3  = (const float*)d_in[4];
    float* out = (float*)d_out;

    char* ws = (char*)d_ws;
    bf16_t* H1hi = (bf16_t*)(ws + (size_t)0 * S_H * 2);
    bf16_t* H1lo = (bf16_t*)(ws + (size_t)1 * S_H * 2);
    bf16_t* H2hi = (bf16_t*)(ws + (size_t)2 * S_H * 2);
    bf16_t* H2lo = (bf16_t*)(ws + (size_t)3 * S_H * 2);
    bf16_t* H3t  = (bf16_t*)(ws + (size_t)4 * S_H * 2);
    size_t off = (size_t)5 * S_H * 2;                    // 41,943,040
    bf16_t* Wthi = (bf16_t*)(ws + off);                  // 393,216 B
    bf16_t* Wtlo = (bf16_t*)(ws + off + 393216);         // 393,216 B
    float* mpart = (float*)(ws + off);                   // overlays Wt (dead after proj)
    float* lpart = (float*)(ws + off + 131072);
    unsigned* adjb = (unsigned*)(ws + off + 786432);     // 524,288 B
    size_t opart_off = off + 786432 + 524288;
    const size_t need2 = opart_off + (size_t)2 * 16384 * 256 * 4;  // ~76.8 MB

    int S = (ws_size >= need2) ? 2 : 1;
    float* Opart = (S == 2) ? (float*)(ws + opart_off) : out;

    adjbits_kernel<<<512, 256, 0, stream>>>(adj, adjb);
    wtrans_kernel<<<dim3(4, 4, 3), 256, 0, stream>>>(W1, W2, W3, Wthi, Wtlo);
    proj_kernel<<<dim3(256, 3), 256, 0, stream>>>(X, Wthi, Wtlo,
                                                  H1hi, H1lo, H2hi, H2lo, H3t);
    attn_kernel<<<dim3(16, 8, S), 512, 0, stream>>>(H1hi, H1lo, H2hi, H2lo, H3t,
                                                    adjb, Opart, mpart, lpart, 2048 / S);
    merge_kernel<<<4096, 256, 0, stream>>>(Opart, mpart, lpart, out, S);
}